// Round 2
// baseline (18.449 us; speedup 1.0000x reference)
//
#include <hip/hip_runtime.h>

// Shift-conv: y[i,n,o] = sum_{k,l} mask_k(o) * ( w[i,l,1,k]*x[l,n,s] + w[i,l,0,k]*x[32+l,(n-1)%56,s] )
// with s = (o+k-2) mod 56.  x:(64,56,56) f32, w:(64,32,2,3) f32, y:(64,56,56) f32  [einsum 'mino'].

__global__ __launch_bounds__(256) void shiftconv_kernel(
    const float* __restrict__ x, const float* __restrict__ w, float* __restrict__ out)
{
    const int n   = blockIdx.x >> 2;   // 0..55  (output spatial row)
    const int ig  = blockIdx.x & 3;    // 0..3   (16 output channels each)
    const int tid = threadIdx.x;

    __shared__ float A[64][56];        // A[c][s]: c<32 -> x[c,n,s] ; c>=32 -> x[c,(n-1)%56,s]
    __shared__ float W[16][64][3];     // W[ii][c][k]: c<32 -> w[i,c,1,k] ; c>=32 -> w[i,c-32,0,k]

    const int hprev = (n + 55) % 56;

    // Stage input slice (3584 floats, coalesced row segments)
    for (int e = tid; e < 64 * 56; e += 256) {
        const int c = e / 56, s = e % 56;
        const int h = (c < 32) ? n : hprev;
        A[c][s] = x[c * 3136 + h * 56 + s];
    }
    // Stage weight slice (3072 floats)
    for (int e = tid; e < 16 * 64 * 3; e += 256) {
        const int ii = e / 192, r = e % 192;
        const int c = r / 3, k = r % 3;
        const int i = ig * 16 + ii;
        const int l = (c < 32) ? c : (c - 32);
        const int j = (c < 32) ? 1 : 0;
        W[ii][c][k] = w[i * 192 + l * 6 + j * 3 + k];
    }
    __syncthreads();

    // 16 channels x 56 cols = 896 outputs per block
    for (int p = tid; p < 16 * 56; p += 256) {
        const int ii = p / 56, o = p % 56;
        float acc = 0.f;

        if (o >= 1) {                       // k = 0, s = (o-2) mod 56
            const int s = (o + 54) % 56;
            #pragma unroll
            for (int c = 0; c < 64; ++c) acc += W[ii][c][0] * A[c][s];
        }
        {                                   // k = 1, s = (o-1) mod 56
            const int s = (o + 55) % 56;
            #pragma unroll
            for (int c = 0; c < 64; ++c) acc += W[ii][c][1] * A[c][s];
        }
        if (o <= 54) {                      // k = 2, s = o
            const int s = o;
            #pragma unroll
            for (int c = 0; c < 64; ++c) acc += W[ii][c][2] * A[c][s];
        }

        // y[m,i,n,o]  (einsum output 'mino' -> shape (1,64,56,56))
        out[(ig * 16 + ii) * 3136 + n * 56 + o] = acc;
    }
}

extern "C" void kernel_launch(void* const* d_in, const int* in_sizes, int n_in,
                              void* d_out, int out_size, void* d_ws, size_t ws_size,
                              hipStream_t stream) {
    const float* x = (const float*)d_in[0];   // (1,64,56,56)
    const float* w = (const float*)d_in[1];   // (64,32,2,3)
    float* out = (float*)d_out;               // (1,64,56,56)

    shiftconv_kernel<<<224, 256, 0, stream>>>(x, w, out);
}

// Round 4
// 14.129 us; speedup vs baseline: 1.3058x; 1.3058x over previous
//
#include <hip/hip_runtime.h>

// Shift-conv: y[i,n,o] = sum_{k,c} W[ii][k][c] * Az[o+k][c]
// where Az[e] is the pre-rolled, zero-padded input row tile (e=0,57 -> 0),
// Az[e][c] = x[c_src, h(c), (e+54)%56],  c<32: h=n, j=1 weights; c>=32: h=(n-1)%56, j=0.
// x:(64,56,56) f32, w:(64,32,2,3) f32, y:(64,56,56) f32 (einsum 'mino').

#define PAD 68   // row stride in floats: 272B = 17*16 -> float4-aligned, banks spread

__global__ __launch_bounds__(128) void shiftconv_kernel(
    const float* __restrict__ x, const float* __restrict__ w, float* __restrict__ out)
{
    const int n   = blockIdx.x >> 2;   // 0..55  output spatial row
    const int ig  = blockIdx.x & 3;    // 0..3   16 output channels each
    const int tid = threadIdx.x;       // 128 threads = 16 ii x 8 og

    __shared__ float Az[58 * PAD];     // Az[e][c], e = o+k in [0,58)
    __shared__ float Ws[16 * 3 * PAD]; // Ws[ii][k][c]

    const int hprev = (n + 55) % 56;

    // zero pad rows e=0 and e=57 (tid covers 0..67 in one shot)
    if (tid < PAD) {
        Az[tid] = 0.f;
        Az[57 * PAD + tid] = 0.f;
    }

    // stage x -> Az with the roll folded in; float4 global loads along s
    for (int idx = tid; idx < 64 * 14; idx += 128) {
        const int c = idx / 14, q = idx % 14;
        const int h = (c < 32) ? n : hprev;
        const float4 v = *(const float4*)(x + c * 3136 + h * 56 + 4 * q);
        const float vv[4] = {v.x, v.y, v.z, v.w};
        #pragma unroll
        for (int j = 0; j < 4; ++j) {
            const int s = 4 * q + j;
            const int e = 1 + ((s + 1) % 56);          // s=(e+54)%56 inverse
            Az[e * PAD + c] = vv[j];
        }
    }

    // stage w -> Ws[ii][k][c]  (c<32: j=1; c>=32: j=0)
    for (int idx = tid; idx < 16 * 192; idx += 128) {
        const int ii = idx / 192, r = idx % 192;
        const int k = r / 64, c = r % 64;
        const int i = ig * 16 + ii;
        const int l = (c < 32) ? c : c - 32;
        const int j = (c < 32) ? 1 : 0;
        Ws[(ii * 3 + k) * PAD + c] = w[i * 192 + l * 6 + j * 3 + k];
    }
    __syncthreads();

    const int ii = tid >> 3;           // 0..15
    const int og = tid & 7;            // 0..7
    const int ob = og * 7;             // base o, 7 outputs per thread

    float acc[7] = {0.f, 0.f, 0.f, 0.f, 0.f, 0.f, 0.f};
    const float* Wi = &Ws[ii * 3 * PAD];
    const float* Ab = &Az[ob * PAD];

    #pragma unroll 4
    for (int c4 = 0; c4 < 64; c4 += 4) {
        float4 wv[3], av[9];
        #pragma unroll
        for (int k = 0; k < 3; ++k) wv[k] = *(const float4*)(Wi + k * PAD + c4);
        #pragma unroll
        for (int d = 0; d < 9; ++d) av[d] = *(const float4*)(Ab + d * PAD + c4);
        #pragma unroll
        for (int oo = 0; oo < 7; ++oo) {
            #pragma unroll
            for (int k = 0; k < 3; ++k) {
                acc[oo] += wv[k].x * av[oo + k].x + wv[k].y * av[oo + k].y
                         + wv[k].z * av[oo + k].z + wv[k].w * av[oo + k].w;
            }
        }
    }

    float* op = out + (ig * 16 + ii) * 3136 + n * 56 + ob;
    #pragma unroll
    for (int oo = 0; oo < 7; ++oo) op[oo] = acc[oo];
}

extern "C" void kernel_launch(void* const* d_in, const int* in_sizes, int n_in,
                              void* d_out, int out_size, void* d_ws, size_t ws_size,
                              hipStream_t stream) {
    const float* x = (const float*)d_in[0];   // (1,64,56,56)
    const float* w = (const float*)d_in[1];   // (64,32,2,3)
    float* out = (float*)d_out;               // (1,64,56,56)

    shiftconv_kernel<<<224, 128, 0, stream>>>(x, w, out);
}

// Round 5
// 12.740 us; speedup vs baseline: 1.4481x; 1.1090x over previous
//
#include <hip/hip_runtime.h>

// Shift-conv: y[i,n,o] = sum_{k,c} W[ii][k][c] * Az[o+k][c]
// Az[e] is the pre-rolled, zero-padded input row tile (e=0,57 -> 0),
// Az[e][c] = x[c_src, h(c), (e+54)%56],  c<32: row n, j=1 weights; c>=32: row (n-1)%56, j=0.
// x:(64,56,56) f32, w:(64,32,2,3) f32, y:(64,56,56) f32 (einsum 'mino').
//
// 128 threads = {c-half h:2} x {ii-pair p:8} x {og:8}; each thread: 2 out-channels x 7 outputs
// over 32 input channels; halves reduced through LDS.

#define PAD 68   // row stride in floats: 272B = 17*16 -> float4-aligned, banks spread

__global__ __launch_bounds__(128) void shiftconv_kernel(
    const float* __restrict__ x, const float* __restrict__ w, float* __restrict__ out)
{
    const int n   = blockIdx.x >> 2;   // 0..55  output spatial row
    const int ig  = blockIdx.x & 3;    // 0..3   16 output channels each
    const int tid = threadIdx.x;

    __shared__ float Az[58 * PAD];     // Az[e][c], e = o+k in [0,58)
    __shared__ float Ws[16 * 3 * PAD]; // Ws[ii][k][c]
    __shared__ float Rr[64 * 17];      // cross-half reduction buffer

    const int hprev = (n + 55) % 56;

    // zero pad rows e=0 and e=57
    if (tid < PAD) {
        Az[tid] = 0.f;
        Az[57 * PAD + tid] = 0.f;
    }

    // stage x -> Az with the roll folded in; float4 global loads along s
    for (int idx = tid; idx < 64 * 14; idx += 128) {
        const int c = idx / 14, q = idx % 14;
        const int h = (c < 32) ? n : hprev;
        const float4 v = *(const float4*)(x + c * 3136 + h * 56 + 4 * q);
        const float vv[4] = {v.x, v.y, v.z, v.w};
        #pragma unroll
        for (int j = 0; j < 4; ++j) {
            const int s = 4 * q + j;
            const int e = 1 + ((s + 1) % 56);          // s=(e+54)%56 inverse
            Az[e * PAD + c] = vv[j];
        }
    }

    // stage w -> Ws[ii][k][c]  (c<32: j=1; c>=32: j=0)
    for (int idx = tid; idx < 16 * 192; idx += 128) {
        const int ii = idx / 192, r = idx % 192;
        const int k = r / 64, c = r % 64;
        const int i = ig * 16 + ii;
        const int l = (c < 32) ? c : c - 32;
        const int j = (c < 32) ? 1 : 0;
        Ws[(ii * 3 + k) * PAD + c] = w[i * 192 + l * 6 + j * 3 + k];
    }
    __syncthreads();

    const int ch = tid >> 6;           // 0/1: channel half (== wave id)
    const int p  = (tid >> 3) & 7;     // ii pair
    const int og = tid & 7;            // output group
    const int ob = og * 7;             // base o, 7 outputs per thread

    float acc[2][7] = {};
    const float* W0 = &Ws[(2 * p) * 3 * PAD + ch * 32];
    const float* W1 = &Ws[(2 * p + 1) * 3 * PAD + ch * 32];
    const float* Ab = &Az[ob * PAD + ch * 32];

    #pragma unroll
    for (int j = 0; j < 8; ++j) {      // 8 chunks of 4 channels within this half
        const int c4 = 4 * j;
        float4 wv0[3], wv1[3], av[9];
        #pragma unroll
        for (int k = 0; k < 3; ++k) {
            wv0[k] = *(const float4*)(W0 + k * PAD + c4);
            wv1[k] = *(const float4*)(W1 + k * PAD + c4);
        }
        #pragma unroll
        for (int d = 0; d < 9; ++d) av[d] = *(const float4*)(Ab + d * PAD + c4);
        #pragma unroll
        for (int oo = 0; oo < 7; ++oo) {
            #pragma unroll
            for (int k = 0; k < 3; ++k) {
                const float4 a = av[oo + k];
                acc[0][oo] += wv0[k].x * a.x + wv0[k].y * a.y + wv0[k].z * a.z + wv0[k].w * a.w;
                acc[1][oo] += wv1[k].x * a.x + wv1[k].y * a.y + wv1[k].z * a.z + wv1[k].w * a.w;
            }
        }
    }

    // cross-half reduction: wave 1 (ch=1) writes partials, wave 0 adds + stores
    const int r = tid & 63;
    if (ch == 1) {
        #pragma unroll
        for (int i2 = 0; i2 < 2; ++i2)
            #pragma unroll
            for (int oo = 0; oo < 7; ++oo)
                Rr[r * 17 + i2 * 8 + oo] = acc[i2][oo];
    }
    __syncthreads();
    if (ch == 0) {
        #pragma unroll
        for (int i2 = 0; i2 < 2; ++i2) {
            float* op = out + (ig * 16 + 2 * p + i2) * 3136 + n * 56 + ob;
            #pragma unroll
            for (int oo = 0; oo < 7; ++oo)
                op[oo] = acc[i2][oo] + Rr[r * 17 + i2 * 8 + oo];
        }
    }
}

extern "C" void kernel_launch(void* const* d_in, const int* in_sizes, int n_in,
                              void* d_out, int out_size, void* d_ws, size_t ws_size,
                              hipStream_t stream) {
    const float* x = (const float*)d_in[0];   // (1,64,56,56)
    const float* w = (const float*)d_in[1];   // (64,32,2,3)
    float* out = (float*)d_out;               // (1,64,56,56)

    shiftconv_kernel<<<224, 128, 0, stream>>>(x, w, out);
}